// Round 15
// baseline (132.459 us; speedup 1.0000x reference)
//
#include <hip/hip_runtime.h>

// LSTM B=4096, T=512, I=1, H=32 — MFMA, round 15: r14 + chain micro-surgery.
//
// r14 (120.4us, chain 565cy) verified structure kept verbatim:
//   block = 128 threads = 2 waves, 4 batches; wave w owns cells col+16w
//   (1 cell/lane) via gate tiles {w,w+2,w+4,w+6}; fp16 h (RNE, no residual);
//   A-rows 4b = batch b h, k-perm cell c <-> k=2*(c&15)+(c>>4); gate scales
//   folded into weights/bias; double-buffered LDS, 1 __syncthreads/step.
//
// Round-15 chain deletions (no structural change):
//  1. xt*W_ih folded into the MFMA C-operand: cb[j]=fma(xt,wih,bias) depends
//     only on xt -> issues during the ds_read latency window; post-MFMA
//     gt = acc[0] directly (fmaf removed from serial path).
//  2. i*G = i*(2rG-1) = fma(rG, 2i, -i), 2i computed parallel to rG's rcp.
//  3. h  = o*(2rc-1) = fma(rc, 2o, -o), 2o computed parallel to rc's rcp.

typedef float f32x4 __attribute__((ext_vector_type(4)));
typedef _Float16 f16x8 __attribute__((ext_vector_type(8)));

#define L2E 1.44269504088896340736f
#define MFMA16(a, b, c) __builtin_amdgcn_mfma_f32_16x16x32_f16((a), (b), (c), 0, 0, 0)

union H2U { _Float16 h; unsigned short u; };

__device__ __forceinline__ float rcp1p(float e) {     // 1/(1+e)
    return __builtin_amdgcn_rcpf(1.0f + e);
}

#define RSTR 40   // u16 row stride: 80B rows, 16B-aligned, banks spread

__global__ __launch_bounds__(128, 2) void lstm_mfma_kernel(
    const float* __restrict__ x,      // [B, 512]
    const float* __restrict__ W_ih,   // [128]
    const float* __restrict__ W_hh,   // [128, 32]
    const float* __restrict__ b_ih,   // [128]
    const float* __restrict__ b_hh,   // [128]
    const float* __restrict__ W_lin,  // [32]
    const float* __restrict__ b_lin,  // [1]
    float* __restrict__ out,          // [B]
    int B)
{
    __shared__ unsigned short Hb[2][8][RSTR];   // [buf][2*batch + hi/lo][RSTR]
    __shared__ float plds[4][2];

    const int tid  = (int)threadIdx.x;
    const int w    = tid >> 6;            // wave 0/1 -> cells col / col+16
    const int lane = tid & 63;
    const int col  = lane & 15;           // tile col = A-row index
    const int g    = lane >> 4;           // batch slot & k-group

    // zero both buffers (h(0)=0; lo rows stay zero forever)
    for (int i = tid; i < 2 * 8 * RSTR; i += 128)
        ((unsigned short*)Hb)[i] = 0;

    // A-row content: col%4==0 -> h(batch col/4); ==1 -> zero row; ==2/3 -> alias 0/1
    const int m4   = col & 3;
    const int rrow = (m4 == 0) ? 2 * (col >> 2)
                   : (m4 == 1) ? 2 * (col >> 2) + 1
                   : (m4 - 2);
    const unsigned short* Ard0 = &Hb[0][rrow][8 * g];   // 16B-aligned
    const unsigned short* Ard1 = &Hb[1][rrow][8 * g];

    // h publish: this lane's cell -> u16 at k = 2*col + w, row (g, hi)
    unsigned short* Whi0 = &Hb[0][2 * g][2 * col + w];
    unsigned short* Whi1 = &Hb[1][2 * g][2 * col + w];

    // B-fragments for this wave's 4 tiles (t = w+2j; j = i,f,G,o): fp16,
    // scales folded. u16 pair jj = (cell g*4+jj, cell g*4+jj+16)  [k-perm]
    f16x8 bf[4];
    float wihs[4];
    float bias0[4];
#pragma unroll
    for (int j = 0; j < 4; ++j) {
        const int t  = w + 2 * j;
        const int gr = t * 16 + col;
        const float sc = (j == 2) ? (-2.0f * L2E) : (-L2E);
        const float* wr = &W_hh[gr * 32];
        float4 wA = *reinterpret_cast<const float4*>(&wr[g * 4]);       // cells g4+0..3
        float4 wB = *reinterpret_cast<const float4*>(&wr[g * 4 + 16]);  // cells g4+16..19
        f16x8 bb;
        bb[0] = (_Float16)(wA.x * sc); bb[1] = (_Float16)(wB.x * sc);
        bb[2] = (_Float16)(wA.y * sc); bb[3] = (_Float16)(wB.y * sc);
        bb[4] = (_Float16)(wA.z * sc); bb[5] = (_Float16)(wB.z * sc);
        bb[6] = (_Float16)(wA.w * sc); bb[7] = (_Float16)(wB.w * sc);
        bf[j] = bb;
        wihs[j] = W_ih[gr] * sc;
        bias0[j] = (b_ih[gr] + b_hh[gr]) * sc;
    }

    const int b_glob = blockIdx.x * 4 + g;
    const int bc     = b_glob < B ? b_glob : (B - 1);
    const float* xb  = x + (size_t)bc * 512;

    float4 xA = *reinterpret_cast<const float4*>(xb);
    float4 xB = *reinterpret_cast<const float4*>(xb + 4);

    float cc = 0.0f, hh = 0.0f;
    __syncthreads();                                    // zero-init visible

    for (int tc = 0; tc < 64; ++tc) {
        const int nbase = ((tc + 1) & 63) * 8;
        const float4 nA = *reinterpret_cast<const float4*>(xb + nbase);
        const float4 nB = *reinterpret_cast<const float4*>(xb + nbase + 4);
        const float xts[8] = {xA.x, xA.y, xA.z, xA.w, xB.x, xB.y, xB.z, xB.w};

#pragma unroll
        for (int s = 0; s < 8; ++s) {
            const float xt = xts[s];

            // C-operand: bias + xt*W_ih, computed during the ds_read window
            // (depends only on xt -> off the h-chain)
            f32x4 C0 = {fmaf(xt, wihs[0], bias0[0]), 0.0f, 0.0f, 0.0f};
            f32x4 C1 = {fmaf(xt, wihs[1], bias0[1]), 0.0f, 0.0f, 0.0f};
            f32x4 C2 = {fmaf(xt, wihs[2], bias0[2]), 0.0f, 0.0f, 0.0f};
            f32x4 C3 = {fmaf(xt, wihs[3], bias0[3]), 0.0f, 0.0f, 0.0f};

            // even global step reads buf0 (h starts in buf0), writes buf1
            const f16x8 af = *reinterpret_cast<const f16x8*>((s & 1) ? Ard1 : Ard0);

            // 4 independent MFMAs; reg0 = h*W + bias + xt*wih; reg1.. dead
            f32x4 a0 = MFMA16(af, bf[0], C0);
            f32x4 a1 = MFMA16(af, bf[1], C1);
            f32x4 a2 = MFMA16(af, bf[2], C2);
            f32x4 a3 = MFMA16(af, bf[3], C3);

            // gates (inputs pre-scaled): sigmoid = rcp(1+exp2(t))
            const float i_ = rcp1p(__builtin_amdgcn_exp2f(a0[0]));
            const float f_ = rcp1p(__builtin_amdgcn_exp2f(a1[0]));
            const float rG = rcp1p(__builtin_amdgcn_exp2f(a2[0]));
            const float o_ = rcp1p(__builtin_amdgcn_exp2f(a3[0]));

            // i*G = i*(2rG-1) = fma(rG, 2i, -i); 2i parallel to rG's rcp
            const float i2 = i_ + i_;
            const float iG = fmaf(rG, i2, -i_);
            cc = fmaf(f_, cc, iG);

            // h = o*tanh(cc) = fma(rc, 2o, -o); 2o parallel to rc's chain
            const float o2 = o_ + o_;
            const float rc = rcp1p(__builtin_amdgcn_exp2f(cc * (-2.0f * L2E)));
            hh = fmaf(rc, o2, -o_);

            // publish h as fp16 (RNE) to the OTHER buffer — single b16 store
            H2U hc; hc.h = (_Float16)hh;
            *((s & 1) ? Whi0 : Whi1) = hc.u;
            __syncthreads();
        }
        xA = nA; xB = nB;
    }

    // out[b] = sum_cells h*W_lin + b_lin: 16-lane reduce, then cross-wave via LDS
    float part = hh * W_lin[col + 16 * w];
#pragma unroll
    for (int off = 8; off; off >>= 1) part += __shfl_xor(part, off, 64);
    if (col == 0) plds[g][w] = part;
    __syncthreads();
    if (w == 0 && col == 0 && b_glob < B)
        out[b_glob] = plds[g][0] + plds[g][1] + b_lin[0];
}

extern "C" void kernel_launch(void* const* d_in, const int* in_sizes, int n_in,
                              void* d_out, int out_size, void* d_ws, size_t ws_size,
                              hipStream_t stream) {
    const float* x     = (const float*)d_in[0];
    const float* W_ih  = (const float*)d_in[1];
    const float* W_hh  = (const float*)d_in[2];
    const float* b_ih  = (const float*)d_in[3];
    const float* b_hh  = (const float*)d_in[4];
    const float* W_lin = (const float*)d_in[5];
    const float* b_lin = (const float*)d_in[6];
    float* out = (float*)d_out;

    const int B = in_sizes[0] / 512;          // x is [B, 512, 1]
    const int blocks = (B + 3) / 4;           // 4 batches per 128-thread block

    lstm_mfma_kernel<<<blocks, 128, 0, stream>>>(x, W_ih, W_hh, b_ih, b_hh,
                                                 W_lin, b_lin, out, B);
}

// Round 16
// 121.972 us; speedup vs baseline: 1.0860x; 1.0860x over previous
//
#include <hip/hip_runtime.h>

// LSTM B=4096, T=512, I=1, H=32 — MFMA, round 16: r14 + critical-path-only cuts.
//
// r15 post-mortem: C-operand fold put a VALU->MFMA hazard in front of every
// MFMA (C was loop-invariant before) -> +10%. Reverted. This round keeps r14
// verbatim (120.4us, chain 565cy) and applies ONLY serial-chain deletions:
//  1. c carried pre-scaled: cs = c*(-2log2e); cs = fma(f, cs, iGs) with
//     iGs = (i*G)*(-2log2e) computed on the off-path i-side. Deletes the
//     cc*(-2L2E) mul from the f->c->h serial chain.
//  2. h = fma(rc, 2o, -o): tanh-finalize + mul fused; 2o computed parallel
//     to rc's exp2/rcp.
//  3. f-tile MFMA issued first (critical chain head start).
//
// Structure (verified r9/r11/r14): block = 128 threads = 2 waves, 4 batches.
// Wave w owns cells col+16w (1 cell/lane) via gate tiles {w,w+2,w+4,w+6}.
// fp16 h (RNE, no residual); A-rows 4b = batch b h, others zero/alias (dead
// D-rows). k-perm: cell c <-> k = 2*(c&15)+(c>>4). Gate scales folded into
// W_ih/W_hh/bias. Double-buffered LDS, one __syncthreads per step.

typedef float f32x4 __attribute__((ext_vector_type(4)));
typedef _Float16 f16x8 __attribute__((ext_vector_type(8)));

#define L2E 1.44269504088896340736f
#define MFMA16(a, b, c) __builtin_amdgcn_mfma_f32_16x16x32_f16((a), (b), (c), 0, 0, 0)

union H2U { _Float16 h; unsigned short u; };

__device__ __forceinline__ float rcp1p(float e) {     // 1/(1+e)
    return __builtin_amdgcn_rcpf(1.0f + e);
}

#define RSTR 40   // u16 row stride: 80B rows, 16B-aligned, banks spread

__global__ __launch_bounds__(128, 2) void lstm_mfma_kernel(
    const float* __restrict__ x,      // [B, 512]
    const float* __restrict__ W_ih,   // [128]
    const float* __restrict__ W_hh,   // [128, 32]
    const float* __restrict__ b_ih,   // [128]
    const float* __restrict__ b_hh,   // [128]
    const float* __restrict__ W_lin,  // [32]
    const float* __restrict__ b_lin,  // [1]
    float* __restrict__ out,          // [B]
    int B)
{
    __shared__ unsigned short Hb[2][8][RSTR];   // [buf][2*batch + hi/lo][RSTR]
    __shared__ float plds[4][2];

    const int tid  = (int)threadIdx.x;
    const int w    = tid >> 6;            // wave 0/1 -> cells col / col+16
    const int lane = tid & 63;
    const int col  = lane & 15;           // tile col = A-row index
    const int g    = lane >> 4;           // batch slot & k-group

    // zero both buffers (h(0)=0; lo rows stay zero forever)
    for (int i = tid; i < 2 * 8 * RSTR; i += 128)
        ((unsigned short*)Hb)[i] = 0;

    // A-row content: col%4==0 -> h(batch col/4); ==1 -> zero row; ==2/3 -> alias 0/1
    const int m4   = col & 3;
    const int rrow = (m4 == 0) ? 2 * (col >> 2)
                   : (m4 == 1) ? 2 * (col >> 2) + 1
                   : (m4 - 2);
    const unsigned short* Ard0 = &Hb[0][rrow][8 * g];   // 16B-aligned
    const unsigned short* Ard1 = &Hb[1][rrow][8 * g];

    // h publish: this lane's cell -> u16 at k = 2*col + w, row (g, hi)
    unsigned short* Whi0 = &Hb[0][2 * g][2 * col + w];
    unsigned short* Whi1 = &Hb[1][2 * g][2 * col + w];

    // B-fragments for this wave's 4 tiles (t = w+2j; j = i,f,G,o): fp16,
    // scales folded. u16 pair jj = (cell g*4+jj, cell g*4+jj+16)  [k-perm]
    f16x8 bf[4];
    float wihs[4];
    f32x4 biasC[4];
#pragma unroll
    for (int j = 0; j < 4; ++j) {
        const int t  = w + 2 * j;
        const int gr = t * 16 + col;
        const float sc = (j == 2) ? (-2.0f * L2E) : (-L2E);
        const float* wr = &W_hh[gr * 32];
        float4 wA = *reinterpret_cast<const float4*>(&wr[g * 4]);       // cells g4+0..3
        float4 wB = *reinterpret_cast<const float4*>(&wr[g * 4 + 16]);  // cells g4+16..19
        f16x8 bb;
        bb[0] = (_Float16)(wA.x * sc); bb[1] = (_Float16)(wB.x * sc);
        bb[2] = (_Float16)(wA.y * sc); bb[3] = (_Float16)(wB.y * sc);
        bb[4] = (_Float16)(wA.z * sc); bb[5] = (_Float16)(wB.z * sc);
        bb[6] = (_Float16)(wA.w * sc); bb[7] = (_Float16)(wB.w * sc);
        bf[j] = bb;
        wihs[j] = W_ih[gr] * sc;
        const float bbias = (b_ih[gr] + b_hh[gr]) * sc;
        biasC[j] = f32x4{bbias, 0.0f, 0.0f, 0.0f};     // bias only in reg0
    }

    const int b_glob = blockIdx.x * 4 + g;
    const int bc     = b_glob < B ? b_glob : (B - 1);
    const float* xb  = x + (size_t)bc * 512;

    float4 xA = *reinterpret_cast<const float4*>(xb);
    float4 xB = *reinterpret_cast<const float4*>(xb + 4);

    float cs = 0.0f, hh = 0.0f;           // cs = c * (-2*log2e), scaled cell state
    __syncthreads();                      // zero-init visible

    for (int tc = 0; tc < 64; ++tc) {
        const int nbase = ((tc + 1) & 63) * 8;
        const float4 nA = *reinterpret_cast<const float4*>(xb + nbase);
        const float4 nB = *reinterpret_cast<const float4*>(xb + nbase + 4);
        const float xts[8] = {xA.x, xA.y, xA.z, xA.w, xB.x, xB.y, xB.z, xB.w};

#pragma unroll
        for (int s = 0; s < 8; ++s) {
            const float xt = xts[s];

            // even global step reads buf0 (h starts in buf0), writes buf1
            const f16x8 af = *reinterpret_cast<const f16x8*>((s & 1) ? Ard1 : Ard0);

            // 4 independent MFMAs, f-tile FIRST (critical chain head start);
            // C loop-invariant (no VALU->MFMA dep). reg0 live, reg1.. dead.
            f32x4 a1 = MFMA16(af, bf[1], biasC[1]);   // f gate
            f32x4 a0 = MFMA16(af, bf[0], biasC[0]);   // i gate
            f32x4 a2 = MFMA16(af, bf[2], biasC[2]);   // G (tanh) gate
            f32x4 a3 = MFMA16(af, bf[3], biasC[3]);   // o gate

            // CRITICAL CHAIN: f -> cs -> rc -> h -> cvt -> ds_write
            const float f_ = rcp1p(__builtin_amdgcn_exp2f(fmaf(xt, wihs[1], a1[0])));

            // off-path (parallel with f's exp2/rcp): i, G, o, iGs, o2
            const float i_ = rcp1p(__builtin_amdgcn_exp2f(fmaf(xt, wihs[0], a0[0])));
            const float rG = rcp1p(__builtin_amdgcn_exp2f(fmaf(xt, wihs[2], a2[0])));
            const float o_ = rcp1p(__builtin_amdgcn_exp2f(fmaf(xt, wihs[3], a3[0])));
            const float G_ = fmaf(rG, 2.0f, -1.0f);
            const float iGs = (i_ * G_) * (-2.0f * L2E);
            const float o2 = o_ + o_;

            cs = fmaf(f_, cs, iGs);                   // scaled c update
            const float rc = rcp1p(__builtin_amdgcn_exp2f(cs));
            hh = fmaf(rc, o2, -o_);                   // o * tanh(c)

            // publish h as fp16 (RNE) to the OTHER buffer — single b16 store
            H2U hc; hc.h = (_Float16)hh;
            *((s & 1) ? Whi0 : Whi1) = hc.u;
            __syncthreads();
        }
        xA = nA; xB = nB;
    }

    // out[b] = sum_cells h*W_lin + b_lin: 16-lane reduce, then cross-wave via LDS
    float part = hh * W_lin[col + 16 * w];
#pragma unroll
    for (int off = 8; off; off >>= 1) part += __shfl_xor(part, off, 64);
    if (col == 0) plds[g][w] = part;
    __syncthreads();
    if (w == 0 && col == 0 && b_glob < B)
        out[b_glob] = plds[g][0] + plds[g][1] + b_lin[0];
}

extern "C" void kernel_launch(void* const* d_in, const int* in_sizes, int n_in,
                              void* d_out, int out_size, void* d_ws, size_t ws_size,
                              hipStream_t stream) {
    const float* x     = (const float*)d_in[0];
    const float* W_ih  = (const float*)d_in[1];
    const float* W_hh  = (const float*)d_in[2];
    const float* b_ih  = (const float*)d_in[3];
    const float* b_hh  = (const float*)d_in[4];
    const float* W_lin = (const float*)d_in[5];
    const float* b_lin = (const float*)d_in[6];
    float* out = (float*)d_out;

    const int B = in_sizes[0] / 512;          // x is [B, 512, 1]
    const int blocks = (B + 3) / 4;           // 4 batches per 128-thread block

    lstm_mfma_kernel<<<blocks, 128, 0, stream>>>(x, W_ih, W_hh, b_ih, b_hh,
                                                 W_lin, b_lin, out, B);
}